// Round 11
// baseline (1167.022 us; speedup 1.0000x reference)
//
#include <hip/hip_runtime.h>

typedef short bf16x8 __attribute__((ext_vector_type(8)));
typedef float f32x4  __attribute__((ext_vector_type(4)));
typedef unsigned short u16;

#define B_ 4
#define R_ 36
#define RP 48          // r padded to 3 m-tiles of 16
#define C_ 3
#define H_ 384
#define W_ 224
#define KS 64
#define OY 321         // conv-out rows needed
#define OX 161         // conv-out cols needed
#define HC 320
#define WC 160
#define LCOLS 128      // staged cols per WG
#define PITCH 104      // rows addr space per col: 96 used (88 + XOR-8 reach), 52 dw -> 8-bank base period
#define BLKS_PER_BATCH 7200

__device__ __forceinline__ u16 bf16rtn(float v) {
    union { float f; unsigned u; } U; U.f = v;
    unsigned r = U.u + 0x7fffu + ((U.u >> 16) & 1u);
    return (u16)(r >> 16);
}
__device__ __forceinline__ float bf16tof(u16 h) {
    union { float f; unsigned u; } U; U.u = ((unsigned)h) << 16; return U.f;
}

__device__ __forceinline__ float wave_max(float v) {
    #pragma unroll
    for (int off = 32; off > 0; off >>= 1) v = fmaxf(v, __shfl_down(v, off, 64));
    return v;
}
__device__ __forceinline__ float wave_sum(float v) {
    #pragma unroll
    for (int off = 32; off > 0; off >>= 1) v += __shfl_down(v, off, 64);
    return v;
}

// Split fp32 weights into bf16 hi/lo planes, transposed to [b][r48][c][kx][ky], r>=36 zeroed.
__global__ __launch_bounds__(256) void prep_weights(
    const float* __restrict__ wk, u16* __restrict__ wh, u16* __restrict__ wl)
{
    int d = blockIdx.x * 256 + threadIdx.x;           // [0, 4*48*3*64*64)
    int ky = d & 63;
    int kx = (d >> 6) & 63;
    int rc = d >> 12;                                  // (b*48+r)*3 + c
    int c  = rc % 3;
    int br = rc / 3;
    int r  = br % RP;
    int b  = br / RP;
    float v = 0.f;
    if (r < R_) v = wk[(((size_t)(b*R_ + r)*C_ + c)*KS + (size_t)ky)*KS + kx];
    u16 h = bf16rtn(v);
    float lo = v - bf16tof(h);
    wh[d] = h;
    wl[d] = bf16rtn(lo);
}

__device__ __forceinline__ void loadA(
    const u16* __restrict__ wth, const u16* __restrict__ wtl,
    int b, int c, int kx, int kyc, int nu, int q,
    bf16x8 (&Ah)[3], bf16x8 (&Al)[3])
{
    #pragma unroll
    for (int mi = 0; mi < 3; mi++) {
        size_t off = ((((size_t)(b*RP + mi*16 + nu)*C_ + c)*KS + kx)*KS) + kyc + 8*q;
        Ah[mi] = *(const bf16x8*)(wth + off);
        Al[mi] = *(const bf16x8*)(wtl + off);
    }
}

// B-read with bank swizzle: row' = row ^ 8*((col>>3)&1). The XOR bit depends
// only on (nu+kx) bit 3 (n*16 never touches bit 3), so it's n-invariant.
template<int NT>
__device__ __forceinline__ void computeChunk(
    const u16* __restrict__ Lh, int kx, int kyc, int nu, int q, int w,
    const bf16x8 (&Ah)[3], const bf16x8 (&Al)[3], f32x4 (&acc)[3][NT])
{
    const int u  = nu + kx;
    const int rb = (kyc + 8*q + 8*w) ^ (8*((u >> 3) & 1));
    const u16* base = Lh + (size_t)u*PITCH + rb;
    #pragma unroll
    for (int n = 0; n < NT; n++) {
        const u16* ph = base + n*16*PITCH;
        bf16x8 Bh = *(const bf16x8*)ph;
        bf16x8 Bl = *(const bf16x8*)(ph + (size_t)LCOLS*PITCH);
        #pragma unroll
        for (int mi = 0; mi < 3; mi++) {
            acc[mi][n] = __builtin_amdgcn_mfma_f32_16x16x32_bf16(Ah[mi], Bh, acc[mi][n], 0, 0, 0);
            acc[mi][n] = __builtin_amdgcn_mfma_f32_16x16x32_bf16(Ah[mi], Bl, acc[mi][n], 0, 0, 0);
            acc[mi][n] = __builtin_amdgcn_mfma_f32_16x16x32_bf16(Al[mi], Bh, acc[mi][n], 0, 0, 0);
        }
    }
}

// Implicit-GEMM conv, MFMA 16x16x32 bf16, 3-product hi/lo split.
// r11: 4 waves = 4 y (y0+8w), all waves share kx (A addrs identical -> L1).
// A = global->VGPR X/Y prefetch (acc only 48 regs, fits 3 waves/SIMD).
// LDS = B only (53 KB -> 3 WG/CU), PITCH 104 + row-XOR swizzle; staging is
// col-per-lane with 4-row b64 writes (no 16-way write conflicts).
// No per-kx barriers. All acc indices compile-time (r5 lesson).
template<int NT>
__device__ __forceinline__ void conv_body(
    const float* __restrict__ in, const u16* __restrict__ wth, const u16* __restrict__ wtl,
    float* __restrict__ out, u16* Lh, u16* Ll, int x0, int y0)
{
    const int b    = blockIdx.z;
    const int t    = threadIdx.x;
    const int w    = __builtin_amdgcn_readfirstlane(t >> 6);
    const int lane = t & 63;
    const int nu   = lane & 15;
    const int q    = lane >> 4;

    f32x4 acc[3][NT];
    #pragma unroll
    for (int mi = 0; mi < 3; mi++)
        #pragma unroll
        for (int n = 0; n < NT; n++)
            acc[mi][n] = (f32x4){0.f, 0.f, 0.f, 0.f};

    bf16x8 AhX[3], AlX[3], AhY[3], AlY[3];
    loadA(wth, wtl, b, 0, 0, 0, nu, q, AhX, AlX);   // first chunk, in flight over staging

    for (int c = 0; c < C_; c++) {
        __syncthreads();
        // ---- stage rows y0..y0+87 (space 0..95 after XOR), cols x0..x0+127 ----
        // item = (col, row-quad): 128 cols x 22 quads = 2816 = 11*256.
        const float* src = in + ((size_t)(b*C_ + c))*H_*W_;
        #pragma unroll
        for (int k = 0; k < 11; k++) {
            int idx  = t + 256*k;
            int col  = idx & 127;
            int quad = idx >> 7;            // 0..21
            int gx   = x0 + col;
            int gy0  = y0 + 4*quad;
            float v0 = 0.f, v1 = 0.f, v2 = 0.f, v3 = 0.f;
            if (gx < W_) {
                const float* p = src + (size_t)gy0*W_ + gx;
                if (gy0     < H_) v0 = p[0];
                if (gy0 + 1 < H_) v1 = p[W_];
                if (gy0 + 2 < H_) v2 = p[2*W_];
                if (gy0 + 3 < H_) v3 = p[3*W_];
            }
            u16 h0 = bf16rtn(v0), h1 = bf16rtn(v1), h2 = bf16rtn(v2), h3 = bf16rtn(v3);
            u16 l0 = bf16rtn(v0 - bf16tof(h0)), l1 = bf16rtn(v1 - bf16tof(h1));
            u16 l2 = bf16rtn(v2 - bf16tof(h2)), l3 = bf16rtn(v3 - bf16tof(h3));
            int rsw = (4*quad) ^ (8*((col >> 3) & 1));   // swizzled row base (4-row block)
            uint2 hv = make_uint2((unsigned)h0 | ((unsigned)h1 << 16),
                                  (unsigned)h2 | ((unsigned)h3 << 16));
            uint2 lv = make_uint2((unsigned)l0 | ((unsigned)l1 << 16),
                                  (unsigned)l2 | ((unsigned)l3 << 16));
            *(uint2*)&Lh[(size_t)col*PITCH + rsw] = hv;
            *(uint2*)&Ll[(size_t)col*PITCH + rsw] = lv;
        }
        __syncthreads();

        // ---- pipelined kx loop: all waves, all kx; A X/Y register prefetch ----
        #pragma unroll 1
        for (int kx = 0; kx < KS; kx++) {
            loadA(wth, wtl, b, c, kx, 32, nu, q, AhY, AlY);          // prefetch (kx,32)
            computeChunk<NT>(Lh, kx, 0, nu, q, w, AhX, AlX, acc);
            if (kx < KS - 1) {
                loadA(wth, wtl, b, c, kx + 1, 0, nu, q, AhX, AlX);   // prefetch (kx+1,0)
            } else if (c + 1 < C_) {
                loadA(wth, wtl, b, c + 1, 0, 0, nu, q, AhX, AlX);    // next channel
            }
            computeChunk<NT>(Lh, kx, 32, nu, q, w, AhY, AlY, acc);
        }
    }

    // ---- direct epilogue: wave owns its y; coalesced stores, no reduction ----
    const int y = y0 + 8*w;
    if (y <= 320) {
        #pragma unroll
        for (int mi = 0; mi < 3; mi++) {
            #pragma unroll
            for (int n = 0; n < NT; n++) {
                #pragma unroll
                for (int i = 0; i < 4; i++) {
                    int r = mi*16 + q*4 + i;     // C/D: row = (lane>>4)*4 + reg
                    int x = x0 + n*16 + nu;      //      col = lane&15
                    if (r < R_ && x < OX)
                        out[((size_t)(b*R_ + r)*OY + y)*OX + x] = acc[mi][n][i];
                }
            }
        }
    }
}

__global__ __launch_bounds__(256) void conv_mfma(
    const float* __restrict__ in, const u16* __restrict__ wth, const u16* __restrict__ wtl,
    float* __restrict__ out)
{
    __shared__ __align__(16) u16 smem[2 * LCOLS * PITCH];   // 53248 B -> 3 WG/CU
    u16* Lh = smem;
    u16* Ll = smem + LCOLS * PITCH;
    // y mapping: s<80 -> y0 = 32*(s>>3) + (s&7); waves cover y0+{0,8,16,24}.
    // s==80 -> y0=320 (waves 1..3 compute on zero-fill, skip stores).
    const int s  = blockIdx.y;
    const int y0 = (s < 80) ? (((s >> 3) << 5) + (s & 7)) : 320;

    if (blockIdx.x == 0)      conv_body<4>(in, wth, wtl, out, Lh, Ll, 0,   y0);
    else if (blockIdx.x == 1) conv_body<4>(in, wth, wtl, out, Lh, Ll, 64,  y0);
    else                      conv_body<3>(in, wth, wtl, out, Lh, Ll, 128, y0);
}

// Bilinear resize (iy==i, ix==j for the needed range) + per-block max partials.
__global__ __launch_bounds__(256) void resize_kernel(
    const float* __restrict__ cv, float* __restrict__ out, float* __restrict__ pmax)
{
    const int t = threadIdx.x;
    const int idx = blockIdx.x * 256 + t;
    const int j = idx % WC;
    const int rest = idx / WC;
    const int i = rest % HC;
    const int br = rest / HC;

    float fy = (i + 32.5f) * (1.0f/384.0f);
    float fx = (j + 32.5f) * (1.0f/224.0f);

    const float* p = cv + ((size_t)br*OY + i)*OX + j;
    float v00 = p[0], v01 = p[1], v10 = p[OX], v11 = p[OX+1];
    float v = (1.f-fy)*((1.f-fx)*v00 + fx*v01) + fy*((1.f-fx)*v10 + fx*v11);
    out[idx] = v;

    __shared__ float sm[4];
    float m = wave_max(v);
    if ((t & 63) == 0) sm[t >> 6] = m;
    __syncthreads();
    if (t == 0) pmax[blockIdx.x] = fmaxf(fmaxf(sm[0], sm[1]), fmaxf(sm[2], sm[3]));
}

__global__ __launch_bounds__(256) void reduce_kernel(
    const float* __restrict__ part, float* __restrict__ res, int n, int is_sum)
{
    const int b = blockIdx.x;
    const int t = threadIdx.x;
    const float* p = part + (size_t)b*n;
    float v = is_sum ? 0.f : -3.0e38f;
    for (int k = t; k < n; k += 256) v = is_sum ? (v + p[k]) : fmaxf(v, p[k]);
    __shared__ float sm[4];
    float w = is_sum ? wave_sum(v) : wave_max(v);
    if ((t & 63) == 0) sm[t >> 6] = w;
    __syncthreads();
    if (t == 0) {
        res[b] = is_sum ? (sm[0]+sm[1]+sm[2]+sm[3])
                        : fmaxf(fmaxf(sm[0], sm[1]), fmaxf(sm[2], sm[3]));
    }
}

__global__ __launch_bounds__(256) void exp_kernel(
    float* __restrict__ out, const float* __restrict__ bmax, float* __restrict__ psum)
{
    const int t = threadIdx.x;
    const int idx = blockIdx.x * 256 + t;
    const int b = blockIdx.x / BLKS_PER_BATCH;
    float e = expf(out[idx] - bmax[b]);
    out[idx] = e;
    __shared__ float sm[4];
    float s = wave_sum(e);
    if ((t & 63) == 0) sm[t >> 6] = s;
    __syncthreads();
    if (t == 0) psum[blockIdx.x] = sm[0]+sm[1]+sm[2]+sm[3];
}

__global__ __launch_bounds__(256) void scale_kernel(
    float* __restrict__ out, const float* __restrict__ bsum)
{
    const int idx = blockIdx.x * 256 + threadIdx.x;
    const int b = blockIdx.x / BLKS_PER_BATCH;
    out[idx] = out[idx] / bsum[b];
}

extern "C" void kernel_launch(void* const* d_in, const int* in_sizes, int n_in,
                              void* d_out, int out_size, void* d_ws, size_t ws_size,
                              hipStream_t stream)
{
    const float* logits = (const float*)d_in[0];   // (4,3,384,224) fp32
    const float* wk     = (const float*)d_in[1];   // (144,3,64,64) fp32
    float* out = (float*)d_out;                    // (4,36,320,160) fp32
    char*  wsB = (char*)d_ws;

    // workspace layout (bytes)
    float* convOut = (float*)wsB;                              // 29,768,256 B
    u16*   wth     = (u16*)(wsB + 29768256);                   // 4,718,592 B
    u16*   wtl     = (u16*)(wsB + 29768256 + 4718592);         // 4,718,592 B
    float* pmax    = (float*)(wsB + 29768256 + 2*4718592);     // 28800 f32
    float* psum    = pmax + 28800;
    float* bmax    = psum + 28800;
    float* bsum    = bmax + 8;

    hipLaunchKernelGGL(prep_weights, dim3(9216),  dim3(256), 0, stream, wk, wth, wtl);
    hipLaunchKernelGGL(conv_mfma,    dim3(3, 81, B_), dim3(256), 0, stream, logits, wth, wtl, convOut);
    hipLaunchKernelGGL(resize_kernel, dim3(28800), dim3(256), 0, stream, convOut, out, pmax);
    hipLaunchKernelGGL(reduce_kernel, dim3(4),     dim3(256), 0, stream, pmax, bmax, BLKS_PER_BATCH, 0);
    hipLaunchKernelGGL(exp_kernel,    dim3(28800), dim3(256), 0, stream, out, bmax, psum);
    hipLaunchKernelGGL(reduce_kernel, dim3(4),     dim3(256), 0, stream, psum, bsum, BLKS_PER_BATCH, 1);
    hipLaunchKernelGGL(scale_kernel,  dim3(28800), dim3(256), 0, stream, out, bsum);
}

// Round 12
// 677.792 us; speedup vs baseline: 1.7218x; 1.7218x over previous
//
#include <hip/hip_runtime.h>

typedef short bf16x8 __attribute__((ext_vector_type(8)));
typedef float f32x4  __attribute__((ext_vector_type(4)));
typedef unsigned short u16;

#define B_ 4
#define R_ 36
#define RP 48          // r padded to 3 m-tiles of 16
#define C_ 3
#define H_ 384
#define W_ 224
#define KS 64
#define OY 321         // conv-out rows needed
#define OX 161         // conv-out cols needed
#define HC 320
#define WC 160
#define LCOLS 128      // staged cols per WG
#define PITCH 120      // B rows per col: 64 + 56 (waves at 8w, +32 for 2nd y); 60 dw = even bank spread
#define GR 3072        // u16 per A-granule: 2 planes x 48 r x 32 ky (6 KB)
#define BLKS_PER_BATCH 7200

__device__ __forceinline__ u16 bf16rtn(float v) {
    union { float f; unsigned u; } U; U.f = v;
    unsigned r = U.u + 0x7fffu + ((U.u >> 16) & 1u);
    return (u16)(r >> 16);
}
__device__ __forceinline__ float bf16tof(u16 h) {
    union { float f; unsigned u; } U; U.u = ((unsigned)h) << 16; return U.f;
}

__device__ __forceinline__ float wave_max(float v) {
    #pragma unroll
    for (int off = 32; off > 0; off >>= 1) v = fmaxf(v, __shfl_down(v, off, 64));
    return v;
}
__device__ __forceinline__ float wave_sum(float v) {
    #pragma unroll
    for (int off = 32; off > 0; off >>= 1) v += __shfl_down(v, off, 64);
    return v;
}

__device__ __forceinline__ void dma16(const u16* g, u16* l) {
    __builtin_amdgcn_global_load_lds(
        (const __attribute__((address_space(1))) void*)g,
        (__attribute__((address_space(3))) void*)l, 16, 0, 0);
}

// Weights -> per-(b,c,kx,kyc) 6 KB granules: [plane h/l][r48][ky32], with
// ky swizzle (ky32 ^ 8*(r&3)) baked in (DMA-verbatim, even LDS bank spread).
// r>=36 zeroed. granule index = ((b*3+c)*64 + kx)*2 + kyc.
__global__ __launch_bounds__(256) void prep_weights(
    const float* __restrict__ wk, u16* __restrict__ wa)
{
    int d = blockIdx.x * 256 + threadIdx.x;   // [0, 1536*3072 = 4,718,592)
    int ky32  = d & 31;
    int t1    = d >> 5;
    int r     = t1 % 48;
    int t2    = t1 / 48;
    int plane = t2 & 1;
    int g2    = t2 >> 1;
    int kycp  = g2 & 1;
    int kx    = (g2 >> 1) & 63;
    int bc    = g2 >> 7;
    int c     = bc % 3;
    int b     = bc / 3;
    int ky    = kycp*32 + ky32;
    float v = 0.f;
    if (r < R_) v = wk[(((size_t)(b*R_ + r)*C_ + c)*KS + ky)*KS + kx];
    u16 h = bf16rtn(v);
    u16 o = plane ? bf16rtn(v - bf16tof(h)) : h;
    wa[(size_t)g2*GR + plane*1536 + r*32 + (ky32 ^ ((r & 3) << 3))] = o;
}

// Implicit-GEMM conv, MFMA 16x16x32 bf16, 3-product hi/lo split.
// r12: r10's LDS-DMA A pipeline + 2 y per wave (A-amortization 2x:
// 22 DS reads / 72 MFMA vs 14/36). Wave w owns y-pair (y0+8w, y0+8w+32).
// A granule = 6 KB per (kx,kyc), double-buffered, per-granule
// waitcnt(0)+barrier+prefetch. Direct epilogue. acc indices compile-time.
template<int NT>
__device__ __forceinline__ void conv_body(
    const float* __restrict__ in, const u16* __restrict__ wa,
    float* __restrict__ out, u16* Lh, u16* Ll, u16* Ab, int x0, int y0)
{
    const int b    = blockIdx.z;
    const int t    = threadIdx.x;
    const int w    = __builtin_amdgcn_readfirstlane(t >> 6);
    const int lane = t & 63;
    const int nu   = lane & 15;
    const int q    = lane >> 4;

    f32x4 acc[2][3][NT];
    #pragma unroll
    for (int yi = 0; yi < 2; yi++)
        #pragma unroll
        for (int mi = 0; mi < 3; mi++)
            #pragma unroll
            for (int n = 0; n < NT; n++)
                acc[yi][mi][n] = (f32x4){0.f, 0.f, 0.f, 0.f};

    const u16* gbase = wa + (size_t)(b*384)*GR;   // this batch's 384 granules

    // prologue: prefetch granule 0 into buf 0 (6 KB = 6 x 1KB slices)
    {
        const u16* s0 = gbase + lane*8;
        if (w < 2) { dma16(s0 + (2*w)*512, Ab + (2*w)*512);
                     dma16(s0 + (2*w+1)*512, Ab + (2*w+1)*512); }
        else       { dma16(s0 + (w+2)*512, Ab + (w+2)*512); }
    }

    for (int c = 0; c < C_; c++) {
        __syncthreads();
        // ---- stage B rows y0..y0+119, cols x0..x0+127, transposed + split ----
        // 60 row-pairs x 32 float4-cols = 1920 items over 256 threads (8 iters).
        const float* src = in + ((size_t)(b*C_ + c))*H_*W_;
        #pragma unroll
        for (int k = 0; k < 8; k++) {
            int idx = t + 256*k;
            if (idx < 1920) {
                int pair = idx >> 5;         // 0..59
                int r0   = pair * 2;
                int c4   = (idx & 31) * 4;
                int gx   = x0 + c4;
                int gy   = y0 + r0;
                float4 va = make_float4(0.f,0.f,0.f,0.f), vb = va;
                if (gx < W_) {               // float4 chunks entirely in or out
                    if (gy < H_)     va = *(const float4*)(src + (size_t)gy*W_ + gx);
                    if (gy + 1 < H_) vb = *(const float4*)(src + (size_t)(gy+1)*W_ + gx);
                }
                const float* pa = &va.x;
                const float* pb = &vb.x;
                #pragma unroll
                for (int j = 0; j < 4; j++) {
                    int col = c4 + j;
                    u16 ha = bf16rtn(pa[j]);
                    u16 hb = bf16rtn(pb[j]);
                    u16 la = bf16rtn(pa[j] - bf16tof(ha));
                    u16 lb = bf16rtn(pb[j] - bf16tof(hb));
                    *(unsigned*)&Lh[col*PITCH + r0] = (unsigned)ha | ((unsigned)hb << 16);
                    *(unsigned*)&Ll[col*PITCH + r0] = (unsigned)la | ((unsigned)lb << 16);
                }
            }
        }
        __syncthreads();

        // ---- granule loop: gi = kx*2 + kyc; all waves share the granule ----
        #pragma unroll 1
        for (int gi = 0; gi < 128; gi++) {
            const int g = c*128 + gi;
            __builtin_amdgcn_s_waitcnt(0x3F70);   // vmcnt(0): own DMA done
            __builtin_amdgcn_s_barrier();         // all waves' DMA done; other buf free
            if (g + 1 < 384) {
                const u16* s2 = gbase + (size_t)(g+1)*GR + lane*8;
                u16* d2 = Ab + ((g+1) & 1)*GR;
                if (w < 2) { dma16(s2 + (2*w)*512, d2 + (2*w)*512);
                             dma16(s2 + (2*w+1)*512, d2 + (2*w+1)*512); }
                else       { dma16(s2 + (w+2)*512, d2 + (w+2)*512); }
            }
            const u16* Abp = Ab + (g & 1)*GR;
            const int kx   = gi >> 1;
            const int kycp = gi & 1;

            bf16x8 Ah[3], Al[3];
            #pragma unroll
            for (int mi = 0; mi < 3; mi++) {
                int off = (mi*16 + nu)*32 + ((8*q) ^ ((nu & 3) << 3));
                Ah[mi] = *(const bf16x8*)(Abp + off);
                Al[mi] = *(const bf16x8*)(Abp + 1536 + off);
            }
            const u16* colbase = Lh + (size_t)(nu + kx)*PITCH + 32*kycp + 8*q + 8*w;
            #pragma unroll
            for (int n = 0; n < NT; n++) {
                #pragma unroll
                for (int yi = 0; yi < 2; yi++) {
                    const u16* ph = colbase + n*16*PITCH + 32*yi;
                    bf16x8 Bh = *(const bf16x8*)ph;
                    bf16x8 Bl = *(const bf16x8*)(ph + (size_t)LCOLS*PITCH);
                    #pragma unroll
                    for (int mi = 0; mi < 3; mi++) {
                        acc[yi][mi][n] = __builtin_amdgcn_mfma_f32_16x16x32_bf16(Ah[mi], Bh, acc[yi][mi][n], 0, 0, 0);
                        acc[yi][mi][n] = __builtin_amdgcn_mfma_f32_16x16x32_bf16(Ah[mi], Bl, acc[yi][mi][n], 0, 0, 0);
                        acc[yi][mi][n] = __builtin_amdgcn_mfma_f32_16x16x32_bf16(Al[mi], Bh, acc[yi][mi][n], 0, 0, 0);
                    }
                }
            }
        }
    }

    // ---- direct epilogue: wave owns its 2 y's; coalesced stores ----
    #pragma unroll
    for (int yi = 0; yi < 2; yi++) {
        const int y = y0 + 8*w + 32*yi;
        if (y <= 320) {
            #pragma unroll
            for (int mi = 0; mi < 3; mi++) {
                #pragma unroll
                for (int n = 0; n < NT; n++) {
                    #pragma unroll
                    for (int i = 0; i < 4; i++) {
                        int r = mi*16 + q*4 + i;     // C/D: row = (lane>>4)*4 + reg
                        int x = x0 + n*16 + nu;      //      col = lane&15
                        if (r < R_ && x < OX)
                            out[((size_t)(b*R_ + r)*OY + y)*OX + x] = acc[yi][mi][n][i];
                    }
                }
            }
        }
    }
}

__global__ __launch_bounds__(256) void conv_mfma(
    const float* __restrict__ in, const u16* __restrict__ wa, float* __restrict__ out)
{
    // B: 2 x 128*120 u16 = 61440 B; A: 2 x 6144 B = 12288 B; total 73728 B -> 2 WG/CU
    __shared__ __align__(16) u16 smem[2*LCOLS*PITCH + 2*GR];
    u16* Lh = smem;
    u16* Ll = smem + LCOLS*PITCH;
    u16* Ab = smem + 2*LCOLS*PITCH;
    // y mapping: s<40 -> y0 = 64*(s>>3) + (s&7); waves cover y0 + {8w, 8w+32}
    // = all 8 residues in a 64-row block. s==40 -> y0=320 (only w=0,yi=0 valid).
    const int s  = blockIdx.y;
    const int y0 = (s < 40) ? ((s >> 3)*64 + (s & 7)) : 320;

    if (blockIdx.x == 0)      conv_body<4>(in, wa, out, Lh, Ll, Ab, 0,   y0);
    else if (blockIdx.x == 1) conv_body<4>(in, wa, out, Lh, Ll, Ab, 64,  y0);
    else                      conv_body<3>(in, wa, out, Lh, Ll, Ab, 128, y0);
}

// Bilinear resize (iy==i, ix==j for the needed range) + per-block max partials.
__global__ __launch_bounds__(256) void resize_kernel(
    const float* __restrict__ cv, float* __restrict__ out, float* __restrict__ pmax)
{
    const int t = threadIdx.x;
    const int idx = blockIdx.x * 256 + t;
    const int j = idx % WC;
    const int rest = idx / WC;
    const int i = rest % HC;
    const int br = rest / HC;

    float fy = (i + 32.5f) * (1.0f/384.0f);
    float fx = (j + 32.5f) * (1.0f/224.0f);

    const float* p = cv + ((size_t)br*OY + i)*OX + j;
    float v00 = p[0], v01 = p[1], v10 = p[OX], v11 = p[OX+1];
    float v = (1.f-fy)*((1.f-fx)*v00 + fx*v01) + fy*((1.f-fx)*v10 + fx*v11);
    out[idx] = v;

    __shared__ float sm[4];
    float m = wave_max(v);
    if ((t & 63) == 0) sm[t >> 6] = m;
    __syncthreads();
    if (t == 0) pmax[blockIdx.x] = fmaxf(fmaxf(sm[0], sm[1]), fmaxf(sm[2], sm[3]));
}

__global__ __launch_bounds__(256) void reduce_kernel(
    const float* __restrict__ part, float* __restrict__ res, int n, int is_sum)
{
    const int b = blockIdx.x;
    const int t = threadIdx.x;
    const float* p = part + (size_t)b*n;
    float v = is_sum ? 0.f : -3.0e38f;
    for (int k = t; k < n; k += 256) v = is_sum ? (v + p[k]) : fmaxf(v, p[k]);
    __shared__ float sm[4];
    float w = is_sum ? wave_sum(v) : wave_max(v);
    if ((t & 63) == 0) sm[t >> 6] = w;
    __syncthreads();
    if (t == 0) {
        res[b] = is_sum ? (sm[0]+sm[1]+sm[2]+sm[3])
                        : fmaxf(fmaxf(sm[0], sm[1]), fmaxf(sm[2], sm[3]));
    }
}

__global__ __launch_bounds__(256) void exp_kernel(
    float* __restrict__ out, const float* __restrict__ bmax, float* __restrict__ psum)
{
    const int t = threadIdx.x;
    const int idx = blockIdx.x * 256 + t;
    const int b = blockIdx.x / BLKS_PER_BATCH;
    float e = expf(out[idx] - bmax[b]);
    out[idx] = e;
    __shared__ float sm[4];
    float s = wave_sum(e);
    if ((t & 63) == 0) sm[t >> 6] = s;
    __syncthreads();
    if (t == 0) psum[blockIdx.x] = sm[0]+sm[1]+sm[2]+sm[3];
}

__global__ __launch_bounds__(256) void scale_kernel(
    float* __restrict__ out, const float* __restrict__ bsum)
{
    const int idx = blockIdx.x * 256 + threadIdx.x;
    const int b = blockIdx.x / BLKS_PER_BATCH;
    out[idx] = out[idx] / bsum[b];
}

extern "C" void kernel_launch(void* const* d_in, const int* in_sizes, int n_in,
                              void* d_out, int out_size, void* d_ws, size_t ws_size,
                              hipStream_t stream)
{
    const float* logits = (const float*)d_in[0];   // (4,3,384,224) fp32
    const float* wk     = (const float*)d_in[1];   // (144,3,64,64) fp32
    float* out = (float*)d_out;                    // (4,36,320,160) fp32
    char*  wsB = (char*)d_ws;

    // workspace layout (bytes)
    float* convOut = (float*)wsB;                              // 29,768,256 B
    u16*   wa      = (u16*)(wsB + 29768256);                   // 9,437,184 B
    float* pmax    = (float*)(wsB + 29768256 + 9437184);       // 28800 f32
    float* psum    = pmax + 28800;
    float* bmax    = psum + 28800;
    float* bsum    = bmax + 8;

    hipLaunchKernelGGL(prep_weights, dim3(18432), dim3(256), 0, stream, wk, wa);
    hipLaunchKernelGGL(conv_mfma,    dim3(3, 41, B_), dim3(256), 0, stream, logits, wa, convOut);
    hipLaunchKernelGGL(resize_kernel, dim3(28800), dim3(256), 0, stream, convOut, out, pmax);
    hipLaunchKernelGGL(reduce_kernel, dim3(4),     dim3(256), 0, stream, pmax, bmax, BLKS_PER_BATCH, 0);
    hipLaunchKernelGGL(exp_kernel,    dim3(28800), dim3(256), 0, stream, out, bmax, psum);
    hipLaunchKernelGGL(reduce_kernel, dim3(4),     dim3(256), 0, stream, psum, bsum, BLKS_PER_BATCH, 1);
    hipLaunchKernelGGL(scale_kernel,  dim3(28800), dim3(256), 0, stream, out, bsum);
}